// Round 20
// baseline (248.801 us; speedup 1.0000x reference)
//
#include <hip/hip_runtime.h>
#include <cstdint>
#include <cstddef>

// ---------------------------------------------------------------------------
// SelfAttention (Flux-style): qkv GEMM + bias -> split q,k,v -> RMSNorm(q,k)
// -> RoPE(q,k) -> flash attention -> out [b,n,dim] fp32.
// b=2, n=2048, dim=2048, h=16, d=128. All MFMA work in bf16 (16x16x32).
//
// FINAL (R20 = R19, session best 246.6us; ladder 485.5 -> 246.6):
// R1: XOR-swizzle k_attn LDS (conflicts 1.2e8->1.3e7; attn 347->162us).
// R2: attn VALU diet (scale folded into Q, cvt_pk P-pack) + dbuf.
// R3-R8 gemm: ring-4 + counted vmcnt(8) + conflict-free swizzle
//     f(row)=(row>>1)&3 (PMC=0) + BM=128xBN=384 grid 512 (115us, 897 TF).
// R10/R11 attn: 4 waves dual-q + FIXED-M softmax (static bound M; softmax
//     shift-invariant -> per-tile lane-local exp+add+pack; attn < 114us).
// R18: merged k_cvt (x+W). R19: k_mbound folded into k_attn prologue.
// FALSIFIED escapes (measured): coarse phase-split x3 (R5,R12,R16 --
//     barrier lockstep serializes LDS&MFMA at block scope), reg-cap
//     residency (R6 spill), 128x96/wave tile (R7 spill), ring-2 @8w (R13
//     register-blocked), BN=192 co-residency (R14 FETCH reuse loss),
//     reg X/Y pipeline (R16 -4%). Past ~36%-of-peak needs the full
//     8-phase co-designed schedule (new template, not graftable here).
// ---------------------------------------------------------------------------

#define LOG2E 1.4426950408889634f
#define ATT_SCALE 0.08838834764831845f   // 1/sqrt(128)
#define QSCALE (ATT_SCALE * LOG2E)       // folded into Q at normrope

typedef __attribute__((ext_vector_type(8))) __bf16 bf16x8;
typedef __attribute__((ext_vector_type(4))) __bf16 bf16x4;
typedef __attribute__((ext_vector_type(4))) float f32x4;

__device__ __forceinline__ float b2f(unsigned u) {
  u <<= 16;
  return __builtin_bit_cast(float, u);
}
__device__ __forceinline__ unsigned short f2b(float f) {
  unsigned x = __builtin_bit_cast(unsigned, f);
  return (unsigned short)((x + 0x7fffu + ((x >> 16) & 1u)) >> 16);  // RNE
}
// async global->LDS, 16B per lane; lds dest must be wave-uniform base (+lane*16)
__device__ __forceinline__ void gl16(const void* g, void* l) {
  __builtin_amdgcn_global_load_lds((__attribute__((address_space(1))) void*)(g),
                                   (__attribute__((address_space(3))) void*)(l), 16, 0, 0);
}

// ---------------- fp32 -> bf16 convert (x and W fused, grid-stride) -------
__global__ void k_cvt2(const float4* __restrict__ inx, ushort4* __restrict__ outx, int nx4,
                       const float4* __restrict__ inw, ushort4* __restrict__ outw, int nw4) {
  int i = blockIdx.x * blockDim.x + threadIdx.x;
  int st = gridDim.x * blockDim.x;
  const int tot = nx4 + nw4;
  for (; i < tot; i += st) {
    const float4* ip; ushort4* op; int k;
    if (i < nx4) { ip = inx; op = outx; k = i; }
    else         { ip = inw; op = outw; k = i - nx4; }
    float4 v = ip[k];
    ushort4 o;
    o.x = f2b(v.x); o.y = f2b(v.y); o.z = f2b(v.z); o.w = f2b(v.w);
    op[k] = o;
  }
}

// ---------------- QKV GEMM: C[4096][6144] = A[4096][2048] * W[6144][2048]^T + bias ----
// 128x384 tile, BK=32, 512 threads = 8 waves (2M x 4N); wave = 64x96 out
// (4x6 frags of 16x16x32, acc = 96 AGPR). Grid 32x16 = 512 blocks = 2
// exactly-full passes at 1 block/CU. Ring-4 LDS slots of 32KB (A 8KB +
// B 24KB) = 128KB; stage(t+3) while computing t; counted vmcnt(8)/4/0.
// Swizzle slot ^= (row>>1)&3: conflict-free (R6-verified, PMC=0).
__global__ __launch_bounds__(512, 2) void k_gemm(const unsigned short* __restrict__ A,
                                                 const unsigned short* __restrict__ W,
                                                 const float* __restrict__ bias,
                                                 unsigned short* __restrict__ C) {
  __shared__ __align__(16) unsigned short lds[65536];  // 128KB: 4 x (A[128][32] + B[384][32])
  const int tid = threadIdx.x;
  const int w = tid >> 6, l = tid & 63;
  const int lo = l & 15, hi = l >> 4;
  const int WM = w >> 2, WN = w & 3;
  // bijective XCD swizzle: 512 wgs = 8 XCDs x 64
  const int wg = blockIdx.x;
  const int swz = (wg & 7) * 64 + (wg >> 3);
  const int mbase = (swz >> 4) * 128, nbase = (swz & 15) * 384;

  // staging: per gl16 round 512 threads cover 128 rows x 64B. A = 1 round,
  // B = 3 rounds (4 gl16/thread/step). Source col pre-swizzled; LDS linear.
  const int srow = w * 16 + (l >> 2);                        // row in 128-row round
  const int scol = ((l & 3) * 8) ^ (((srow >> 1) & 3) << 3); // involution per row

  auto stage = [&](int t, int slot) {
    unsigned short* Sa = lds + slot * 16384;   // 32KB slot
    unsigned short* Sb = Sa + 4096;            // A = 8KB
    const int kt = t * 32;
    gl16(A + (size_t)(mbase + srow) * 2048 + kt + scol,
         Sa + (w * 16) * 32);
#pragma unroll
    for (int rd = 0; rd < 3; ++rd)
      gl16(W + (size_t)(nbase + rd * 128 + srow) * 2048 + kt + scol,
           Sb + (rd * 128 + w * 16) * 32);
  };

  f32x4 acc[4][6] = {};
  stage(0, 0); stage(1, 1); stage(2, 2);   // 12 gl16 in flight

  // read-side swizzled element offset: row terms (WM*64, WN*96, i*16) are
  // multiples of 16, so (row>>1)&3 == (lo>>1)&3.
  const int ea = (hi * 8) ^ (((lo >> 1) & 3) << 3);
  for (int t = 0; t < 64; ++t) {
    // lgkmcnt(0)+barrier: all waves' reads of slot t-1 complete => staging
    // slot (t+3)&3 == (t-1)&3 after the barrier is race-free. vmcnt(8):
    // drain slot-t's 4 loads (issued at t-3); 8 newer stay in flight.
    if (t < 62)       asm volatile("s_waitcnt vmcnt(8) lgkmcnt(0)" ::: "memory");
    else if (t == 62) asm volatile("s_waitcnt vmcnt(4) lgkmcnt(0)" ::: "memory");
    else              asm volatile("s_waitcnt vmcnt(0) lgkmcnt(0)" ::: "memory");
    __builtin_amdgcn_sched_barrier(0);
    __builtin_amdgcn_s_barrier();
    __builtin_amdgcn_sched_barrier(0);
    if (t + 3 < 64) stage(t + 3, (t + 3) & 3);

    const unsigned short* Sa = lds + (t & 3) * 16384;
    const unsigned short* Sb = Sa + 4096;
    bf16x8 af[4], bf[6];
#pragma unroll
    for (int i = 0; i < 4; ++i)
      af[i] = *(const bf16x8*)&Sa[(WM * 64 + i * 16 + lo) * 32 + ea];
#pragma unroll
    for (int j = 0; j < 6; ++j)
      bf[j] = *(const bf16x8*)&Sb[(WN * 96 + j * 16 + lo) * 32 + ea];

    __builtin_amdgcn_s_setprio(1);
#pragma unroll
    for (int i = 0; i < 4; ++i)
#pragma unroll
      for (int j = 0; j < 6; ++j)
        acc[i][j] = __builtin_amdgcn_mfma_f32_16x16x32_bf16(af[i], bf[j], acc[i][j], 0, 0, 0);
    __builtin_amdgcn_s_setprio(0);
  }

  const int rowb = mbase + WM * 64;
  const int colb = nbase + WN * 96;
#pragma unroll
  for (int j = 0; j < 6; ++j) {
    float bj = bias[colb + j * 16 + lo];
#pragma unroll
    for (int i = 0; i < 4; ++i)
#pragma unroll
      for (int r = 0; r < 4; ++r) {
        int row = rowb + i * 16 + hi * 4 + r;  // C/D: col=lane&15, row=(lane>>4)*4+reg
        C[(size_t)row * 6144 + colb + j * 16 + lo] = f2b(acc[i][j][r] + bj);
      }
  }
}

// ---------------- RMSNorm + RoPE + split ----------------
// qkv[t][o] bf16, o = h*384 + dd*3 + j (j in {q,k,v}). One wave per (b,n,h),
// 4 waves per block; lane handles pair dd = 2l, 2l+1. Writes Q,K,V in
// [b*h][n][128] bf16. Q pre-scaled by ATT_SCALE*LOG2E.
__global__ __launch_bounds__(256) void k_normrope(const unsigned short* __restrict__ qkv,
                                                  const float* __restrict__ qw,
                                                  const float* __restrict__ kw,
                                                  const float* __restrict__ rot,
                                                  unsigned short* __restrict__ Q,
                                                  unsigned short* __restrict__ K,
                                                  unsigned short* __restrict__ V) {
  const int l = threadIdx.x & 63;
  const int idx = blockIdx.x * 4 + (threadIdx.x >> 6);
  const int h = idx & 15;
  const int n = (idx >> 4) & 2047;
  const int b = idx >> 15;
  const unsigned* p = (const unsigned*)(qkv + (size_t)(b * 2048 + n) * 6144 + h * 384 + l * 6);
  unsigned u0 = p[0], u1 = p[1], u2 = p[2];
  float q0 = b2f(u0 & 0xffff), k0 = b2f(u0 >> 16);
  float v0 = b2f(u1 & 0xffff), q1 = b2f(u1 >> 16);
  float k1 = b2f(u2 & 0xffff), v1 = b2f(u2 >> 16);
  (void)v0; (void)v1;
  float sq = q0 * q0 + q1 * q1, sk = k0 * k0 + k1 * k1;
#pragma unroll
  for (int m = 1; m < 64; m <<= 1) {
    sq += __shfl_xor(sq, m, 64);
    sk += __shfl_xor(sk, m, 64);
  }
  float qi = rsqrtf(sq * (1.0f / 128.0f) + 1e-6f) * QSCALE;  // softmax scale folded in
  float ki = rsqrtf(sk * (1.0f / 128.0f) + 1e-6f);
  float2 qwv = *(const float2*)&qw[2 * l];
  float2 kwv = *(const float2*)&kw[2 * l];
  float4 r = *(const float4*)&rot[n * 256 + l * 4];  // [cos, -sin, sin, cos]
  float qn0 = q0 * qi * qwv.x, qn1 = q1 * qi * qwv.y;
  float kn0 = k0 * ki * kwv.x, kn1 = k1 * ki * kwv.y;
  unsigned qo = (unsigned)f2b(r.x * qn0 + r.y * qn1) | ((unsigned)f2b(r.z * qn0 + r.w * qn1) << 16);
  unsigned ko = (unsigned)f2b(r.x * kn0 + r.y * kn1) | ((unsigned)f2b(r.z * kn0 + r.w * kn1) << 16);
  unsigned vo = (u1 & 0xffffu) | (u2 & 0xffff0000u);  // v passthrough (already bf16)
  size_t ob = ((size_t)(b * 16 + h) * 2048 + n) * 128 + 2 * l;
  *(unsigned*)(Q + ob) = qo;
  *(unsigned*)(K + ob) = ko;
  *(unsigned*)(V + ob) = vo;
}

// ---------------- V transpose: [bh][n][128] -> [bh][128][n] ----------------
__global__ __launch_bounds__(256) void k_transpose(const unsigned short* __restrict__ V,
                                                   unsigned short* __restrict__ Vt) {
  __shared__ unsigned short tile[64 * 66];
  const int t = threadIdx.x;
  const int d0 = blockIdx.x * 64;
  const int n0 = blockIdx.y * 64;
  const int bh = blockIdx.z;
#pragma unroll
  for (int s = t; s < 512; s += 256) {
    int nr = s >> 3, c8 = (s & 7) * 8;
    uint4 vv = *(const uint4*)(V + ((size_t)bh * 2048 + n0 + nr) * 128 + d0 + c8);
    unsigned* tp = (unsigned*)&tile[nr * 66 + c8];
    tp[0] = vv.x; tp[1] = vv.y; tp[2] = vv.z; tp[3] = vv.w;
  }
  __syncthreads();
#pragma unroll
  for (int s = t; s < 512; s += 256) {
    int dr = s >> 3, n8 = (s & 7) * 8;
    unsigned short e[8];
#pragma unroll
    for (int j = 0; j < 8; ++j) e[j] = tile[(n8 + j) * 66 + dr];
    uint4 o;
    o.x = e[0] | ((unsigned)e[1] << 16);
    o.y = e[2] | ((unsigned)e[3] << 16);
    o.z = e[4] | ((unsigned)e[5] << 16);
    o.w = e[6] | ((unsigned)e[7] << 16);
    *(uint4*)(Vt + ((size_t)bh * 128 + d0 + dr) * 2048 + n0 + n8) = o;
  }
}

// ---------------- flash attention ----------------
// R11: 4 waves (256 thr), dual-q (32 q-rows/wave as two 16-row groups),
// QBLK=128, KV tiles of 64 double-buffered (8 gl16/thread/tile), 80KB LDS
// -> 2 blocks/CU. FIXED-M softmax: p = exp2(S - M), M = static bound
// 128*max|qw|*max|kw|*QSCALE (RMSNorm rows ||q^||<=sqrt(128), RoPE
// orthogonal; softmax shift-invariant) computed in-prologue by every wave
// (R19: k_mbound folded in; hidden under stage(0) latency). Per tile the
// softmax is purely lane-local exp+add+pack; l accumulated per-lane with a
// single cross-lane reduce after the KV loop. O staging rows padded to 132.
// All LDS tiles XOR-swizzled: element_off_in_row ^= ((row & 7) << 3).
// Grid 512 = 16 qt x 32 bh, decoded so a head's 16 q-blocks share one XCD.
__global__ __launch_bounds__(256, 2) void k_attn(const unsigned short* __restrict__ Q,
                                                 const unsigned short* __restrict__ K,
                                                 const unsigned short* __restrict__ Vt,
                                                 const float* __restrict__ qw,
                                                 const float* __restrict__ kw,
                                                 float* __restrict__ out) {
  __shared__ __align__(16) unsigned short lds[40960];  // 80KB
  unsigned short* Ps = lds + 32768;                    // 4 waves x 2 x [16][64]
  const int tid = threadIdx.x;
  const int w = tid >> 6, l = tid & 63;
  const int lo = l & 15, hi = l >> 4;
  const int swz = (lo & 7) << 3;       // read-side XOR for row = ...+lo tiles
  // XCD-aware decode: 512 blocks; bh = (id&7)*4 + ((id>>3)&3), qt = id>>5
  // -> the 16 qt blocks of one bh share id%8 -> same XCD (KV 4MB = one L2).
  const int id = blockIdx.x;
  const int bh = (id & 7) * 4 + ((id >> 3) & 3);
  const int qt = id >> 5;
  const unsigned short* Qb = Q + (size_t)bh * 2048 * 128;
  const unsigned short* Kb = K + (size_t)bh * 2048 * 128;
  const unsigned short* Vb = Vt + (size_t)bh * 128 * 2048;
  unsigned short* Pswa = Ps + w * 2048;
  unsigned short* Pswb = Pswa + 1024;

  // Per-thread pre-swizzled source pointers. Row offsets added later (round
  // steps 16/32 rows, tile steps 64 rows) are multiples of 8, so the
  // swizzle XOR term (row&7) is invariant.
  const int krow0 = w * 4 + hi;             // K row within 16-row round
  const int vrow0 = w * 8 + (l >> 3);       // Vt row within 32-row round
  const unsigned short* kp = Kb + (size_t)krow0 * 128 + ((lo * 8) ^ ((krow0 & 7) << 3));
  const unsigned short* vp = Vb + (size_t)vrow0 * 2048 + (((l & 7) * 8) ^ ((vrow0 & 7) << 3));

  // stage KV tile t into buffer b: K[64][128] in 4 rounds of 16 rows,
  // Vts[128][64] in 4 rounds of 32 rows (256 threads).
  auto stage = [&](int t, int b) {
    unsigned short* Ksb = lds + b * 16384;
    unsigned short* Vtsb = Ksb + 8192;
#pragma unroll
    for (int r = 0; r < 4; ++r) {
      gl16(kp + (size_t)t * 8192 + r * 2048,            // 16 rows * 128 per round
           Ksb + (r * 16 + w * 4) * 128);
      gl16(vp + (size_t)r * 65536 + t * 64,             // 32 rows * 2048 per round
           Vtsb + (r * 32 + w * 8) * 64);
    }
  };

  stage(0, 0);   // issue first tile's loads before the M reduce (hides HBM lat)

  // R19: static softmax bound computed in-prologue (was k_mbound).
  float mq = fmaxf(fabsf(qw[l]), fabsf(qw[l + 64]));
  float mk = fmaxf(fabsf(kw[l]), fabsf(kw[l + 64]));
#pragma unroll
  for (int m = 1; m < 64; m <<= 1) {
    mq = fmaxf(mq, __shfl_xor(mq, m, 64));
    mk = fmaxf(mk, __shfl_xor(mk, m, 64));
  }
  const float M = 128.0f * mq * mk * QSCALE;

  bf16x8 qfa[4], qfb[4];
  const int qrow = qt * 128 + w * 32 + lo;
#pragma unroll
  for (int dk = 0; dk < 4; ++dk) {
    qfa[dk] = *(const bf16x8*)&Qb[(size_t)qrow * 128 + dk * 32 + hi * 8];
    qfb[dk] = *(const bf16x8*)&Qb[(size_t)(qrow + 16) * 128 + dk * 32 + hi * 8];
  }

  f32x4 Oa[8] = {}, Ob[8] = {};
  float l_a = 0.0f, l_b = 0.0f;        // per-lane partial denominators

  // fixed-M P-store for one 16-q group: lane-local only.
  auto pstore = [&](f32x4* S, float& l_part, unsigned short* Psw_) {
#pragma unroll
    for (int kf = 0; kf < 4; ++kf) {
      float p0 = exp2f(S[kf][0] - M);
      float p1 = exp2f(S[kf][1] - M);
      float p2 = exp2f(S[kf][2] - M);
      float p3 = exp2f(S[kf][3] - M);
      l_part += (p0 + p1) + (p2 + p3);
      bf16x4 pk;
      pk[0] = (__bf16)p0; pk[1] = (__bf16)p1;
      pk[2] = (__bf16)p2; pk[3] = (__bf16)p3;
      *(bf16x4*)&Psw_[lo * 64 + ((kf * 16 + hi * 4) ^ swz)] = pk;
    }
  };

  int cur = 0;
  for (int t = 0; t < 32; ++t) {
    // __syncthreads drains vmcnt(0)+lgkmcnt(0): staging from last iteration
    // had a full compute phase of slack; all reads of buffer cur^1 are done.
    __syncthreads();
    if (t + 1 < 32) stage(t + 1, cur ^ 1);
    const unsigned short* Ks = lds + cur * 16384;
    const unsigned short* Vts = Ks + 8192;

    f32x4 Sa[4] = {}, Sb[4] = {};
#pragma unroll
    for (int kf = 0; kf < 4; ++kf)
#pragma unroll
      for (int dk = 0; dk < 4; ++dk) {
        const bf16x8 kfrag =
            *(const bf16x8*)&Ks[(kf * 16 + lo) * 128 + ((dk * 32 + hi * 8) ^ swz)];
        Sa[kf] = __builtin_amdgcn_mfma_f32_16x16x32_bf16(kfrag, qfa[dk], Sa[kf], 0, 0, 0);
        Sb[kf] = __builtin_amdgcn_mfma_f32_16x16x32_bf16(kfrag, qfb[dk], Sb[kf], 0, 0, 0);
      }

    pstore(Sa, l_a, Pswa);
    pstore(Sb, l_b, Pswb);

    const bf16x8 pa0 = *(const bf16x8*)&Pswa[lo * 64 + ((hi * 8) ^ swz)];
    const bf16x8 pa1 = *(const bf16x8*)&Pswa[lo * 64 + ((32 + hi * 8) ^ swz)];
    const bf16x8 pb0 = *(const bf16x8*)&Pswb[lo * 64 + ((hi * 8) ^ swz)];
    const bf16x8 pb1 = *(const bf16x8*)&Pswb[lo * 64 + ((32 + hi * 8) ^ swz)];
#pragma unroll
    for (int df = 0; df < 8; ++df) {
      const bf16x8 v0 = *(const bf16x8*)&Vts[(df * 16 + lo) * 64 + ((hi * 8) ^ swz)];
      const bf16x8 v1 = *(const bf16x8*)&Vts[(df * 16 + lo) * 64 + ((32 + hi * 8) ^ swz)];
      Oa[df] = __builtin_amdgcn_mfma_f32_16x16x32_bf16(v0, pa0, Oa[df], 0, 0, 0);
      Oa[df] = __builtin_amdgcn_mfma_f32_16x16x32_bf16(v1, pa1, Oa[df], 0, 0, 0);
      Ob[df] = __builtin_amdgcn_mfma_f32_16x16x32_bf16(v0, pb0, Ob[df], 0, 0, 0);
      Ob[df] = __builtin_amdgcn_mfma_f32_16x16x32_bf16(v1, pb1, Ob[df], 0, 0, 0);
    }
    cur ^= 1;
  }

  // single cross-lane denominator reduce (over the 4 hi groups)
  l_a += __shfl_xor(l_a, 16, 64);
  l_a += __shfl_xor(l_a, 32, 64);
  l_b += __shfl_xor(l_b, 16, 64);
  l_b += __shfl_xor(l_b, 32, 64);
  const float inva = 1.0f / l_a;   // valid for q = lo (replicated across hi)
  const float invb = 1.0f / l_b;
  const int b = bh >> 4, h = bh & 15;
  const int q2 = l >> 2, c = (l & 3) * 32;
  float* Ot = ((float*)lds) + w * 2112;  // [16 q][132 dv pad] per wave (~8.25KB)

  // group A epilogue
  __syncthreads();                 // done with K/V bufs; reuse as fp32 staging
#pragma unroll
  for (int df = 0; df < 8; ++df)
#pragma unroll
    for (int r = 0; r < 4; ++r)
      Ot[lo * 132 + df * 16 + hi * 4 + r] = Oa[df][r] * inva;
  __syncthreads();
  {
    float* op = out + ((size_t)(b * 2048 + qt * 128 + w * 32 + q2) * 2048 + h * 128 + c);
#pragma unroll
    for (int u = 0; u < 8; ++u)
      *(float4*)&op[u * 4] = *(const float4*)&Ot[q2 * 132 + c + u * 4];
  }
  // group B epilogue
  __syncthreads();
#pragma unroll
  for (int df = 0; df < 8; ++df)
#pragma unroll
    for (int r = 0; r < 4; ++r)
      Ot[lo * 132 + df * 16 + hi * 4 + r] = Ob[df][r] * invb;
  __syncthreads();
  {
    float* op = out + ((size_t)(b * 2048 + qt * 128 + w * 32 + 16 + q2) * 2048 + h * 128 + c);
#pragma unroll
    for (int u = 0; u < 8; ++u)
      *(float4*)&op[u * 4] = *(const float4*)&Ot[q2 * 132 + c + u * 4];
  }
}

// ---------------------------------------------------------------------------
extern "C" void kernel_launch(void* const* d_in, const int* in_sizes, int n_in,
                              void* d_out, int out_size, void* d_ws, size_t ws_size,
                              hipStream_t stream) {
  (void)in_sizes; (void)n_in; (void)out_size; (void)ws_size;
  const float* x = (const float*)d_in[0];
  const float* qkv_w = (const float*)d_in[1];
  const float* qkv_b = (const float*)d_in[2];
  const float* q_norm_w = (const float*)d_in[3];
  const float* k_norm_w = (const float*)d_in[4];
  const float* rot = (const float*)d_in[5];
  float* out = (float*)d_out;
  char* ws = (char*)d_ws;
  // ws layout (bytes): xb 16MB | wb 24MB | qkv 48MB | Q 16MB | K 16MB | V 16MB
  // Vt aliases xb region (dead after GEMM). Total required: ~136 MiB.
  unsigned short* xb  = (unsigned short*)(ws);
  unsigned short* wb  = (unsigned short*)(ws + 16777216);
  unsigned short* qkv = (unsigned short*)(ws + 41943040);
  unsigned short* Qb  = (unsigned short*)(ws + 92274688);
  unsigned short* Kb  = (unsigned short*)(ws + 109051904);
  unsigned short* Vb  = (unsigned short*)(ws + 125829120);
  unsigned short* Vtb = (unsigned short*)(ws);  // alias

  hipLaunchKernelGGL(k_cvt2, dim3(2048), dim3(256), 0, stream,
                     (const float4*)x, (ushort4*)xb, 8388608 / 4,
                     (const float4*)qkv_w, (ushort4*)wb, 12582912 / 4);
  hipLaunchKernelGGL(k_gemm, dim3(512), dim3(512), 0, stream, xb, wb, qkv_b, qkv);
  hipLaunchKernelGGL(k_normrope, dim3(16384), dim3(256), 0, stream,
                     qkv, q_norm_w, k_norm_w, rot, Qb, Kb, Vb);
  hipLaunchKernelGGL(k_transpose, dim3(2, 32, 32), dim3(256), 0, stream, Vb, Vtb);
  hipLaunchKernelGGL(k_attn, dim3(512), dim3(256), 0, stream, Qb, Kb, Vtb,
                     q_norm_w, k_norm_w, out);
}

// Round 21
// 247.625 us; speedup vs baseline: 1.0048x; 1.0048x over previous
//
#include <hip/hip_runtime.h>
#include <cstdint>
#include <cstddef>

// ---------------------------------------------------------------------------
// SelfAttention (Flux-style): qkv GEMM + bias -> split q,k,v -> RMSNorm(q,k)
// -> RoPE(q,k) -> flash attention -> out [b,n,dim] fp32.
// b=2, n=2048, dim=2048, h=16, d=128. All MFMA work in bf16 (16x16x32).
//
// FINAL (session best 246.6us; ladder 485.5 -> 246.6):
// R1: XOR-swizzle k_attn LDS (conflicts 1.2e8->1.3e7; attn 347->162us).
// R2: attn VALU diet (scale folded into Q, cvt_pk P-pack) + dbuf.
// R3-R8 gemm: ring-4 + counted vmcnt(8) + conflict-free swizzle
//     f(row)=(row>>1)&3 (PMC=0) + BM=128xBN=384 grid 512 (114us, 900 TF).
// R10/R11 attn: 4 waves dual-q + FIXED-M softmax (static bound M; softmax
//     shift-invariant -> per-tile lane-local exp+add+pack; attn < 114us).
// R18: merged k_cvt (x+W). R19: k_mbound folded into k_attn prologue.
// FALSIFIED escapes (measured): coarse phase-split x3 (R5,R12,R16 --
//     the block-wide barrier is the serializer, not instruction order),
//     reg-cap residency (R6 spill), 128x96/wave tile (R7 spill, 320>256
//     regs incl AGPR), ring-2 @8w (R13: 176 regs -> 2 waves/SIMD cap),
//     BN=192 co-residency (R14: FETCH 205->374MB reuse loss), reg X/Y
//     pipeline (R16 -4%). Past ~36%-of-peak needs the full 8-phase
//     co-designed schedule (new template, not graftable incrementally).
// ---------------------------------------------------------------------------

#define LOG2E 1.4426950408889634f
#define ATT_SCALE 0.08838834764831845f   // 1/sqrt(128)
#define QSCALE (ATT_SCALE * LOG2E)       // folded into Q at normrope

typedef __attribute__((ext_vector_type(8))) __bf16 bf16x8;
typedef __attribute__((ext_vector_type(4))) __bf16 bf16x4;
typedef __attribute__((ext_vector_type(4))) float f32x4;

__device__ __forceinline__ float b2f(unsigned u) {
  u <<= 16;
  return __builtin_bit_cast(float, u);
}
__device__ __forceinline__ unsigned short f2b(float f) {
  unsigned x = __builtin_bit_cast(unsigned, f);
  return (unsigned short)((x + 0x7fffu + ((x >> 16) & 1u)) >> 16);  // RNE
}
// async global->LDS, 16B per lane; lds dest must be wave-uniform base (+lane*16)
__device__ __forceinline__ void gl16(const void* g, void* l) {
  __builtin_amdgcn_global_load_lds((__attribute__((address_space(1))) void*)(g),
                                   (__attribute__((address_space(3))) void*)(l), 16, 0, 0);
}

// ---------------- fp32 -> bf16 convert (x and W fused, grid-stride) -------
__global__ void k_cvt2(const float4* __restrict__ inx, ushort4* __restrict__ outx, int nx4,
                       const float4* __restrict__ inw, ushort4* __restrict__ outw, int nw4) {
  int i = blockIdx.x * blockDim.x + threadIdx.x;
  int st = gridDim.x * blockDim.x;
  const int tot = nx4 + nw4;
  for (; i < tot; i += st) {
    const float4* ip; ushort4* op; int k;
    if (i < nx4) { ip = inx; op = outx; k = i; }
    else         { ip = inw; op = outw; k = i - nx4; }
    float4 v = ip[k];
    ushort4 o;
    o.x = f2b(v.x); o.y = f2b(v.y); o.z = f2b(v.z); o.w = f2b(v.w);
    op[k] = o;
  }
}

// ---------------- QKV GEMM: C[4096][6144] = A[4096][2048] * W[6144][2048]^T + bias ----
// 128x384 tile, BK=32, 512 threads = 8 waves (2M x 4N); wave = 64x96 out
// (4x6 frags of 16x16x32, acc = 96 AGPR). Grid 32x16 = 512 blocks = 2
// exactly-full passes at 1 block/CU. Ring-4 LDS slots of 32KB (A 8KB +
// B 24KB) = 128KB; stage(t+3) while computing t; counted vmcnt(8)/4/0.
// Swizzle slot ^= (row>>1)&3: conflict-free (R6-verified, PMC=0).
__global__ __launch_bounds__(512, 2) void k_gemm(const unsigned short* __restrict__ A,
                                                 const unsigned short* __restrict__ W,
                                                 const float* __restrict__ bias,
                                                 unsigned short* __restrict__ C) {
  __shared__ __align__(16) unsigned short lds[65536];  // 128KB: 4 x (A[128][32] + B[384][32])
  const int tid = threadIdx.x;
  const int w = tid >> 6, l = tid & 63;
  const int lo = l & 15, hi = l >> 4;
  const int WM = w >> 2, WN = w & 3;
  // bijective XCD swizzle: 512 wgs = 8 XCDs x 64
  const int wg = blockIdx.x;
  const int swz = (wg & 7) * 64 + (wg >> 3);
  const int mbase = (swz >> 4) * 128, nbase = (swz & 15) * 384;

  // staging: per gl16 round 512 threads cover 128 rows x 64B. A = 1 round,
  // B = 3 rounds (4 gl16/thread/step). Source col pre-swizzled; LDS linear.
  const int srow = w * 16 + (l >> 2);                        // row in 128-row round
  const int scol = ((l & 3) * 8) ^ (((srow >> 1) & 3) << 3); // involution per row

  auto stage = [&](int t, int slot) {
    unsigned short* Sa = lds + slot * 16384;   // 32KB slot
    unsigned short* Sb = Sa + 4096;            // A = 8KB
    const int kt = t * 32;
    gl16(A + (size_t)(mbase + srow) * 2048 + kt + scol,
         Sa + (w * 16) * 32);
#pragma unroll
    for (int rd = 0; rd < 3; ++rd)
      gl16(W + (size_t)(nbase + rd * 128 + srow) * 2048 + kt + scol,
           Sb + (rd * 128 + w * 16) * 32);
  };

  f32x4 acc[4][6] = {};
  stage(0, 0); stage(1, 1); stage(2, 2);   // 12 gl16 in flight

  // read-side swizzled element offset: row terms (WM*64, WN*96, i*16) are
  // multiples of 16, so (row>>1)&3 == (lo>>1)&3.
  const int ea = (hi * 8) ^ (((lo >> 1) & 3) << 3);
  for (int t = 0; t < 64; ++t) {
    // lgkmcnt(0)+barrier: all waves' reads of slot t-1 complete => staging
    // slot (t+3)&3 == (t-1)&3 after the barrier is race-free. vmcnt(8):
    // drain slot-t's 4 loads (issued at t-3); 8 newer stay in flight.
    if (t < 62)       asm volatile("s_waitcnt vmcnt(8) lgkmcnt(0)" ::: "memory");
    else if (t == 62) asm volatile("s_waitcnt vmcnt(4) lgkmcnt(0)" ::: "memory");
    else              asm volatile("s_waitcnt vmcnt(0) lgkmcnt(0)" ::: "memory");
    __builtin_amdgcn_sched_barrier(0);
    __builtin_amdgcn_s_barrier();
    __builtin_amdgcn_sched_barrier(0);
    if (t + 3 < 64) stage(t + 3, (t + 3) & 3);

    const unsigned short* Sa = lds + (t & 3) * 16384;
    const unsigned short* Sb = Sa + 4096;
    bf16x8 af[4], bf[6];
#pragma unroll
    for (int i = 0; i < 4; ++i)
      af[i] = *(const bf16x8*)&Sa[(WM * 64 + i * 16 + lo) * 32 + ea];
#pragma unroll
    for (int j = 0; j < 6; ++j)
      bf[j] = *(const bf16x8*)&Sb[(WN * 96 + j * 16 + lo) * 32 + ea];

    __builtin_amdgcn_s_setprio(1);
#pragma unroll
    for (int i = 0; i < 4; ++i)
#pragma unroll
      for (int j = 0; j < 6; ++j)
        acc[i][j] = __builtin_amdgcn_mfma_f32_16x16x32_bf16(af[i], bf[j], acc[i][j], 0, 0, 0);
    __builtin_amdgcn_s_setprio(0);
  }

  const int rowb = mbase + WM * 64;
  const int colb = nbase + WN * 96;
#pragma unroll
  for (int j = 0; j < 6; ++j) {
    float bj = bias[colb + j * 16 + lo];
#pragma unroll
    for (int i = 0; i < 4; ++i)
#pragma unroll
      for (int r = 0; r < 4; ++r) {
        int row = rowb + i * 16 + hi * 4 + r;  // C/D: col=lane&15, row=(lane>>4)*4+reg
        C[(size_t)row * 6144 + colb + j * 16 + lo] = f2b(acc[i][j][r] + bj);
      }
  }
}

// ---------------- RMSNorm + RoPE + split ----------------
// qkv[t][o] bf16, o = h*384 + dd*3 + j (j in {q,k,v}). One wave per (b,n,h),
// 4 waves per block; lane handles pair dd = 2l, 2l+1. Writes Q,K,V in
// [b*h][n][128] bf16. Q pre-scaled by ATT_SCALE*LOG2E.
__global__ __launch_bounds__(256) void k_normrope(const unsigned short* __restrict__ qkv,
                                                  const float* __restrict__ qw,
                                                  const float* __restrict__ kw,
                                                  const float* __restrict__ rot,
                                                  unsigned short* __restrict__ Q,
                                                  unsigned short* __restrict__ K,
                                                  unsigned short* __restrict__ V) {
  const int l = threadIdx.x & 63;
  const int idx = blockIdx.x * 4 + (threadIdx.x >> 6);
  const int h = idx & 15;
  const int n = (idx >> 4) & 2047;
  const int b = idx >> 15;
  const unsigned* p = (const unsigned*)(qkv + (size_t)(b * 2048 + n) * 6144 + h * 384 + l * 6);
  unsigned u0 = p[0], u1 = p[1], u2 = p[2];
  float q0 = b2f(u0 & 0xffff), k0 = b2f(u0 >> 16);
  float v0 = b2f(u1 & 0xffff), q1 = b2f(u1 >> 16);
  float k1 = b2f(u2 & 0xffff), v1 = b2f(u2 >> 16);
  (void)v0; (void)v1;
  float sq = q0 * q0 + q1 * q1, sk = k0 * k0 + k1 * k1;
#pragma unroll
  for (int m = 1; m < 64; m <<= 1) {
    sq += __shfl_xor(sq, m, 64);
    sk += __shfl_xor(sk, m, 64);
  }
  float qi = rsqrtf(sq * (1.0f / 128.0f) + 1e-6f) * QSCALE;  // softmax scale folded in
  float ki = rsqrtf(sk * (1.0f / 128.0f) + 1e-6f);
  float2 qwv = *(const float2*)&qw[2 * l];
  float2 kwv = *(const float2*)&kw[2 * l];
  float4 r = *(const float4*)&rot[n * 256 + l * 4];  // [cos, -sin, sin, cos]
  float qn0 = q0 * qi * qwv.x, qn1 = q1 * qi * qwv.y;
  float kn0 = k0 * ki * kwv.x, kn1 = k1 * ki * kwv.y;
  unsigned qo = (unsigned)f2b(r.x * qn0 + r.y * qn1) | ((unsigned)f2b(r.z * qn0 + r.w * qn1) << 16);
  unsigned ko = (unsigned)f2b(r.x * kn0 + r.y * kn1) | ((unsigned)f2b(r.z * kn0 + r.w * kn1) << 16);
  unsigned vo = (u1 & 0xffffu) | (u2 & 0xffff0000u);  // v passthrough (already bf16)
  size_t ob = ((size_t)(b * 16 + h) * 2048 + n) * 128 + 2 * l;
  *(unsigned*)(Q + ob) = qo;
  *(unsigned*)(K + ob) = ko;
  *(unsigned*)(V + ob) = vo;
}

// ---------------- V transpose: [bh][n][128] -> [bh][128][n] ----------------
__global__ __launch_bounds__(256) void k_transpose(const unsigned short* __restrict__ V,
                                                   unsigned short* __restrict__ Vt) {
  __shared__ unsigned short tile[64 * 66];
  const int t = threadIdx.x;
  const int d0 = blockIdx.x * 64;
  const int n0 = blockIdx.y * 64;
  const int bh = blockIdx.z;
#pragma unroll
  for (int s = t; s < 512; s += 256) {
    int nr = s >> 3, c8 = (s & 7) * 8;
    uint4 vv = *(const uint4*)(V + ((size_t)bh * 2048 + n0 + nr) * 128 + d0 + c8);
    unsigned* tp = (unsigned*)&tile[nr * 66 + c8];
    tp[0] = vv.x; tp[1] = vv.y; tp[2] = vv.z; tp[3] = vv.w;
  }
  __syncthreads();
#pragma unroll
  for (int s = t; s < 512; s += 256) {
    int dr = s >> 3, n8 = (s & 7) * 8;
    unsigned short e[8];
#pragma unroll
    for (int j = 0; j < 8; ++j) e[j] = tile[(n8 + j) * 66 + dr];
    uint4 o;
    o.x = e[0] | ((unsigned)e[1] << 16);
    o.y = e[2] | ((unsigned)e[3] << 16);
    o.z = e[4] | ((unsigned)e[5] << 16);
    o.w = e[6] | ((unsigned)e[7] << 16);
    *(uint4*)(Vt + ((size_t)bh * 128 + d0 + dr) * 2048 + n0 + n8) = o;
  }
}

// ---------------- flash attention ----------------
// R11: 4 waves (256 thr), dual-q (32 q-rows/wave as two 16-row groups),
// QBLK=128, KV tiles of 64 double-buffered (8 gl16/thread/tile), 80KB LDS
// -> 2 blocks/CU. FIXED-M softmax: p = exp2(S - M), M = static bound
// 128*max|qw|*max|kw|*QSCALE (RMSNorm rows ||q^||<=sqrt(128), RoPE
// orthogonal; softmax shift-invariant) computed in-prologue by every wave
// (R19: k_mbound folded in; hidden under stage(0) latency). Per tile the
// softmax is purely lane-local exp+add+pack; l accumulated per-lane with a
// single cross-lane reduce after the KV loop. O staging rows padded to 132.
// All LDS tiles XOR-swizzled: element_off_in_row ^= ((row & 7) << 3).
// Grid 512 = 16 qt x 32 bh, decoded so a head's 16 q-blocks share one XCD.
__global__ __launch_bounds__(256, 2) void k_attn(const unsigned short* __restrict__ Q,
                                                 const unsigned short* __restrict__ K,
                                                 const unsigned short* __restrict__ Vt,
                                                 const float* __restrict__ qw,
                                                 const float* __restrict__ kw,
                                                 float* __restrict__ out) {
  __shared__ __align__(16) unsigned short lds[40960];  // 80KB
  unsigned short* Ps = lds + 32768;                    // 4 waves x 2 x [16][64]
  const int tid = threadIdx.x;
  const int w = tid >> 6, l = tid & 63;
  const int lo = l & 15, hi = l >> 4;
  const int swz = (lo & 7) << 3;       // read-side XOR for row = ...+lo tiles
  // XCD-aware decode: 512 blocks; bh = (id&7)*4 + ((id>>3)&3), qt = id>>5
  // -> the 16 qt blocks of one bh share id%8 -> same XCD (KV 4MB = one L2).
  const int id = blockIdx.x;
  const int bh = (id & 7) * 4 + ((id >> 3) & 3);
  const int qt = id >> 5;
  const unsigned short* Qb = Q + (size_t)bh * 2048 * 128;
  const unsigned short* Kb = K + (size_t)bh * 2048 * 128;
  const unsigned short* Vb = Vt + (size_t)bh * 128 * 2048;
  unsigned short* Pswa = Ps + w * 2048;
  unsigned short* Pswb = Pswa + 1024;

  // Per-thread pre-swizzled source pointers. Row offsets added later (round
  // steps 16/32 rows, tile steps 64 rows) are multiples of 8, so the
  // swizzle XOR term (row&7) is invariant.
  const int krow0 = w * 4 + hi;             // K row within 16-row round
  const int vrow0 = w * 8 + (l >> 3);       // Vt row within 32-row round
  const unsigned short* kp = Kb + (size_t)krow0 * 128 + ((lo * 8) ^ ((krow0 & 7) << 3));
  const unsigned short* vp = Vb + (size_t)vrow0 * 2048 + (((l & 7) * 8) ^ ((vrow0 & 7) << 3));

  // stage KV tile t into buffer b: K[64][128] in 4 rounds of 16 rows,
  // Vts[128][64] in 4 rounds of 32 rows (256 threads).
  auto stage = [&](int t, int b) {
    unsigned short* Ksb = lds + b * 16384;
    unsigned short* Vtsb = Ksb + 8192;
#pragma unroll
    for (int r = 0; r < 4; ++r) {
      gl16(kp + (size_t)t * 8192 + r * 2048,            // 16 rows * 128 per round
           Ksb + (r * 16 + w * 4) * 128);
      gl16(vp + (size_t)r * 65536 + t * 64,             // 32 rows * 2048 per round
           Vtsb + (r * 32 + w * 8) * 64);
    }
  };

  stage(0, 0);   // issue first tile's loads before the M reduce (hides HBM lat)

  // R19: static softmax bound computed in-prologue (was k_mbound).
  float mq = fmaxf(fabsf(qw[l]), fabsf(qw[l + 64]));
  float mk = fmaxf(fabsf(kw[l]), fabsf(kw[l + 64]));
#pragma unroll
  for (int m = 1; m < 64; m <<= 1) {
    mq = fmaxf(mq, __shfl_xor(mq, m, 64));
    mk = fmaxf(mk, __shfl_xor(mk, m, 64));
  }
  const float M = 128.0f * mq * mk * QSCALE;

  bf16x8 qfa[4], qfb[4];
  const int qrow = qt * 128 + w * 32 + lo;
#pragma unroll
  for (int dk = 0; dk < 4; ++dk) {
    qfa[dk] = *(const bf16x8*)&Qb[(size_t)qrow * 128 + dk * 32 + hi * 8];
    qfb[dk] = *(const bf16x8*)&Qb[(size_t)(qrow + 16) * 128 + dk * 32 + hi * 8];
  }

  f32x4 Oa[8] = {}, Ob[8] = {};
  float l_a = 0.0f, l_b = 0.0f;        // per-lane partial denominators

  // fixed-M P-store for one 16-q group: lane-local only.
  auto pstore = [&](f32x4* S, float& l_part, unsigned short* Psw_) {
#pragma unroll
    for (int kf = 0; kf < 4; ++kf) {
      float p0 = exp2f(S[kf][0] - M);
      float p1 = exp2f(S[kf][1] - M);
      float p2 = exp2f(S[kf][2] - M);
      float p3 = exp2f(S[kf][3] - M);
      l_part += (p0 + p1) + (p2 + p3);
      bf16x4 pk;
      pk[0] = (__bf16)p0; pk[1] = (__bf16)p1;
      pk[2] = (__bf16)p2; pk[3] = (__bf16)p3;
      *(bf16x4*)&Psw_[lo * 64 + ((kf * 16 + hi * 4) ^ swz)] = pk;
    }
  };

  int cur = 0;
  for (int t = 0; t < 32; ++t) {
    // __syncthreads drains vmcnt(0)+lgkmcnt(0): staging from last iteration
    // had a full compute phase of slack; all reads of buffer cur^1 are done.
    __syncthreads();
    if (t + 1 < 32) stage(t + 1, cur ^ 1);
    const unsigned short* Ks = lds + cur * 16384;
    const unsigned short* Vts = Ks + 8192;

    f32x4 Sa[4] = {}, Sb[4] = {};
#pragma unroll
    for (int kf = 0; kf < 4; ++kf)
#pragma unroll
      for (int dk = 0; dk < 4; ++dk) {
        const bf16x8 kfrag =
            *(const bf16x8*)&Ks[(kf * 16 + lo) * 128 + ((dk * 32 + hi * 8) ^ swz)];
        Sa[kf] = __builtin_amdgcn_mfma_f32_16x16x32_bf16(kfrag, qfa[dk], Sa[kf], 0, 0, 0);
        Sb[kf] = __builtin_amdgcn_mfma_f32_16x16x32_bf16(kfrag, qfb[dk], Sb[kf], 0, 0, 0);
      }

    pstore(Sa, l_a, Pswa);
    pstore(Sb, l_b, Pswb);

    const bf16x8 pa0 = *(const bf16x8*)&Pswa[lo * 64 + ((hi * 8) ^ swz)];
    const bf16x8 pa1 = *(const bf16x8*)&Pswa[lo * 64 + ((32 + hi * 8) ^ swz)];
    const bf16x8 pb0 = *(const bf16x8*)&Pswb[lo * 64 + ((hi * 8) ^ swz)];
    const bf16x8 pb1 = *(const bf16x8*)&Pswb[lo * 64 + ((32 + hi * 8) ^ swz)];
#pragma unroll
    for (int df = 0; df < 8; ++df) {
      const bf16x8 v0 = *(const bf16x8*)&Vts[(df * 16 + lo) * 64 + ((hi * 8) ^ swz)];
      const bf16x8 v1 = *(const bf16x8*)&Vts[(df * 16 + lo) * 64 + ((32 + hi * 8) ^ swz)];
      Oa[df] = __builtin_amdgcn_mfma_f32_16x16x32_bf16(v0, pa0, Oa[df], 0, 0, 0);
      Oa[df] = __builtin_amdgcn_mfma_f32_16x16x32_bf16(v1, pa1, Oa[df], 0, 0, 0);
      Ob[df] = __builtin_amdgcn_mfma_f32_16x16x32_bf16(v0, pb0, Ob[df], 0, 0, 0);
      Ob[df] = __builtin_amdgcn_mfma_f32_16x16x32_bf16(v1, pb1, Ob[df], 0, 0, 0);
    }
    cur ^= 1;
  }

  // single cross-lane denominator reduce (over the 4 hi groups)
  l_a += __shfl_xor(l_a, 16, 64);
  l_a += __shfl_xor(l_a, 32, 64);
  l_b += __shfl_xor(l_b, 16, 64);
  l_b += __shfl_xor(l_b, 32, 64);
  const float inva = 1.0f / l_a;   // valid for q = lo (replicated across hi)
  const float invb = 1.0f / l_b;
  const int b = bh >> 4, h = bh & 15;
  const int q2 = l >> 2, c = (l & 3) * 32;
  float* Ot = ((float*)lds) + w * 2112;  // [16 q][132 dv pad] per wave (~8.25KB)

  // group A epilogue
  __syncthreads();                 // done with K/V bufs; reuse as fp32 staging
#pragma unroll
  for (int df = 0; df < 8; ++df)
#pragma unroll
    for (int r = 0; r < 4; ++r)
      Ot[lo * 132 + df * 16 + hi * 4 + r] = Oa[df][r] * inva;
  __syncthreads();
  {
    float* op = out + ((size_t)(b * 2048 + qt * 128 + w * 32 + q2) * 2048 + h * 128 + c);
#pragma unroll
    for (int u = 0; u < 8; ++u)
      *(float4*)&op[u * 4] = *(const float4*)&Ot[q2 * 132 + c + u * 4];
  }
  // group B epilogue
  __syncthreads();
#pragma unroll
  for (int df = 0; df < 8; ++df)
#pragma unroll
    for (int r = 0; r < 4; ++r)
      Ot[lo * 132 + df * 16 + hi * 4 + r] = Ob[df][r] * invb;
  __syncthreads();
  {
    float* op = out + ((size_t)(b * 2048 + qt * 128 + w * 32 + 16 + q2) * 2048 + h * 128 + c);
#pragma unroll
    for (int u = 0; u < 8; ++u)
      *(float4*)&op[u * 4] = *(const float4*)&Ot[q2 * 132 + c + u * 4];
  }
}

// ---------------------------------------------------------------------------
extern "C" void kernel_launch(void* const* d_in, const int* in_sizes, int n_in,
                              void* d_out, int out_size, void* d_ws, size_t ws_size,
                              hipStream_t stream) {
  (void)in_sizes; (void)n_in; (void)out_size; (void)ws_size;
  const float* x = (const float*)d_in[0];
  const float* qkv_w = (const float*)d_in[1];
  const float* qkv_b = (const float*)d_in[2];
  const float* q_norm_w = (const float*)d_in[3];
  const float* k_norm_w = (const float*)d_in[4];
  const float* rot = (const float*)d_in[5];
  float* out = (float*)d_out;
  char* ws = (char*)d_ws;
  // ws layout (bytes): xb 16MB | wb 24MB | qkv 48MB | Q 16MB | K 16MB | V 16MB
  // Vt aliases xb region (dead after GEMM). Total required: ~136 MiB.
  unsigned short* xb  = (unsigned short*)(ws);
  unsigned short* wb  = (unsigned short*)(ws + 16777216);
  unsigned short* qkv = (unsigned short*)(ws + 41943040);
  unsigned short* Qb  = (unsigned short*)(ws + 92274688);
  unsigned short* Kb  = (unsigned short*)(ws + 109051904);
  unsigned short* Vb  = (unsigned short*)(ws + 125829120);
  unsigned short* Vtb = (unsigned short*)(ws);  // alias

  hipLaunchKernelGGL(k_cvt2, dim3(2048), dim3(256), 0, stream,
                     (const float4*)x, (ushort4*)xb, 8388608 / 4,
                     (const float4*)qkv_w, (ushort4*)wb, 12582912 / 4);
  hipLaunchKernelGGL(k_gemm, dim3(512), dim3(512), 0, stream, xb, wb, qkv_b, qkv);
  hipLaunchKernelGGL(k_normrope, dim3(16384), dim3(256), 0, stream,
                     qkv, q_norm_w, k_norm_w, rot, Qb, Kb, Vb);
  hipLaunchKernelGGL(k_transpose, dim3(2, 32, 32), dim3(256), 0, stream, Vb, Vtb);
  hipLaunchKernelGGL(k_attn, dim3(512), dim3(256), 0, stream, Qb, Kb, Vtb,
                     q_norm_w, k_norm_w, out);
}

// Round 22
// 246.480 us; speedup vs baseline: 1.0094x; 1.0046x over previous
//
#include <hip/hip_runtime.h>
#include <cstdint>
#include <cstddef>

// ---------------------------------------------------------------------------
// SelfAttention (Flux-style): qkv GEMM + bias -> split q,k,v -> RMSNorm(q,k)
// -> RoPE(q,k) -> flash attention -> out [b,n,dim] fp32.
// b=2, n=2048, dim=2048, h=16, d=128. All MFMA work in bf16 (16x16x32).
//
// FINAL (session best 246.6us, 3x reproduced 246.6/248.8/247.6;
// ladder 485.5 -> 246.6 = 1.97x):
// R1: XOR-swizzle k_attn LDS (conflicts 1.2e8->1.3e7; attn 347->162us).
// R2: attn VALU diet (scale folded into Q, cvt_pk P-pack) + dbuf.
// R3-R8 gemm: ring-4 + counted vmcnt(8) + conflict-free swizzle
//     f(row)=(row>>1)&3 (PMC=0) + BM=128xBN=384 grid 512 (114us, 900 TF).
// R10/R11 attn: 4 waves dual-q + FIXED-M softmax (static bound M; softmax
//     shift-invariant -> per-tile lane-local exp+add+pack; attn < 114us).
// R18: merged k_cvt (x+W). R19: k_mbound folded into k_attn prologue.
// FALSIFIED escapes (measured): coarse phase-split x3 (R5,R12,R16 --
//     the block-wide barrier is the serializer, not instruction order),
//     reg-cap residency (R6 spill), 128x96/wave tile (R7 spill, 320>256
//     regs incl AGPR), ring-2 @8w (R13: 176 regs -> 2 waves/SIMD cap),
//     BN=192 co-residency (R14: FETCH 205->374MB reuse loss), reg X/Y
//     pipeline (R16 -4%). Past ~36%-of-peak needs the full 8-phase
//     co-designed schedule (new template, not graftable incrementally).
// ---------------------------------------------------------------------------

#define LOG2E 1.4426950408889634f
#define ATT_SCALE 0.08838834764831845f   // 1/sqrt(128)
#define QSCALE (ATT_SCALE * LOG2E)       // folded into Q at normrope

typedef __attribute__((ext_vector_type(8))) __bf16 bf16x8;
typedef __attribute__((ext_vector_type(4))) __bf16 bf16x4;
typedef __attribute__((ext_vector_type(4))) float f32x4;

__device__ __forceinline__ float b2f(unsigned u) {
  u <<= 16;
  return __builtin_bit_cast(float, u);
}
__device__ __forceinline__ unsigned short f2b(float f) {
  unsigned x = __builtin_bit_cast(unsigned, f);
  return (unsigned short)((x + 0x7fffu + ((x >> 16) & 1u)) >> 16);  // RNE
}
// async global->LDS, 16B per lane; lds dest must be wave-uniform base (+lane*16)
__device__ __forceinline__ void gl16(const void* g, void* l) {
  __builtin_amdgcn_global_load_lds((__attribute__((address_space(1))) void*)(g),
                                   (__attribute__((address_space(3))) void*)(l), 16, 0, 0);
}

// ---------------- fp32 -> bf16 convert (x and W fused, grid-stride) -------
__global__ void k_cvt2(const float4* __restrict__ inx, ushort4* __restrict__ outx, int nx4,
                       const float4* __restrict__ inw, ushort4* __restrict__ outw, int nw4) {
  int i = blockIdx.x * blockDim.x + threadIdx.x;
  int st = gridDim.x * blockDim.x;
  const int tot = nx4 + nw4;
  for (; i < tot; i += st) {
    const float4* ip; ushort4* op; int k;
    if (i < nx4) { ip = inx; op = outx; k = i; }
    else         { ip = inw; op = outw; k = i - nx4; }
    float4 v = ip[k];
    ushort4 o;
    o.x = f2b(v.x); o.y = f2b(v.y); o.z = f2b(v.z); o.w = f2b(v.w);
    op[k] = o;
  }
}

// ---------------- QKV GEMM: C[4096][6144] = A[4096][2048] * W[6144][2048]^T + bias ----
// 128x384 tile, BK=32, 512 threads = 8 waves (2M x 4N); wave = 64x96 out
// (4x6 frags of 16x16x32, acc = 96 AGPR). Grid 32x16 = 512 blocks = 2
// exactly-full passes at 1 block/CU. Ring-4 LDS slots of 32KB (A 8KB +
// B 24KB) = 128KB; stage(t+3) while computing t; counted vmcnt(8)/4/0.
// Swizzle slot ^= (row>>1)&3: conflict-free (R6-verified, PMC=0).
__global__ __launch_bounds__(512, 2) void k_gemm(const unsigned short* __restrict__ A,
                                                 const unsigned short* __restrict__ W,
                                                 const float* __restrict__ bias,
                                                 unsigned short* __restrict__ C) {
  __shared__ __align__(16) unsigned short lds[65536];  // 128KB: 4 x (A[128][32] + B[384][32])
  const int tid = threadIdx.x;
  const int w = tid >> 6, l = tid & 63;
  const int lo = l & 15, hi = l >> 4;
  const int WM = w >> 2, WN = w & 3;
  // bijective XCD swizzle: 512 wgs = 8 XCDs x 64
  const int wg = blockIdx.x;
  const int swz = (wg & 7) * 64 + (wg >> 3);
  const int mbase = (swz >> 4) * 128, nbase = (swz & 15) * 384;

  // staging: per gl16 round 512 threads cover 128 rows x 64B. A = 1 round,
  // B = 3 rounds (4 gl16/thread/step). Source col pre-swizzled; LDS linear.
  const int srow = w * 16 + (l >> 2);                        // row in 128-row round
  const int scol = ((l & 3) * 8) ^ (((srow >> 1) & 3) << 3); // involution per row

  auto stage = [&](int t, int slot) {
    unsigned short* Sa = lds + slot * 16384;   // 32KB slot
    unsigned short* Sb = Sa + 4096;            // A = 8KB
    const int kt = t * 32;
    gl16(A + (size_t)(mbase + srow) * 2048 + kt + scol,
         Sa + (w * 16) * 32);
#pragma unroll
    for (int rd = 0; rd < 3; ++rd)
      gl16(W + (size_t)(nbase + rd * 128 + srow) * 2048 + kt + scol,
           Sb + (rd * 128 + w * 16) * 32);
  };

  f32x4 acc[4][6] = {};
  stage(0, 0); stage(1, 1); stage(2, 2);   // 12 gl16 in flight

  // read-side swizzled element offset: row terms (WM*64, WN*96, i*16) are
  // multiples of 16, so (row>>1)&3 == (lo>>1)&3.
  const int ea = (hi * 8) ^ (((lo >> 1) & 3) << 3);
  for (int t = 0; t < 64; ++t) {
    // lgkmcnt(0)+barrier: all waves' reads of slot t-1 complete => staging
    // slot (t+3)&3 == (t-1)&3 after the barrier is race-free. vmcnt(8):
    // drain slot-t's 4 loads (issued at t-3); 8 newer stay in flight.
    if (t < 62)       asm volatile("s_waitcnt vmcnt(8) lgkmcnt(0)" ::: "memory");
    else if (t == 62) asm volatile("s_waitcnt vmcnt(4) lgkmcnt(0)" ::: "memory");
    else              asm volatile("s_waitcnt vmcnt(0) lgkmcnt(0)" ::: "memory");
    __builtin_amdgcn_sched_barrier(0);
    __builtin_amdgcn_s_barrier();
    __builtin_amdgcn_sched_barrier(0);
    if (t + 3 < 64) stage(t + 3, (t + 3) & 3);

    const unsigned short* Sa = lds + (t & 3) * 16384;
    const unsigned short* Sb = Sa + 4096;
    bf16x8 af[4], bf[6];
#pragma unroll
    for (int i = 0; i < 4; ++i)
      af[i] = *(const bf16x8*)&Sa[(WM * 64 + i * 16 + lo) * 32 + ea];
#pragma unroll
    for (int j = 0; j < 6; ++j)
      bf[j] = *(const bf16x8*)&Sb[(WN * 96 + j * 16 + lo) * 32 + ea];

    __builtin_amdgcn_s_setprio(1);
#pragma unroll
    for (int i = 0; i < 4; ++i)
#pragma unroll
      for (int j = 0; j < 6; ++j)
        acc[i][j] = __builtin_amdgcn_mfma_f32_16x16x32_bf16(af[i], bf[j], acc[i][j], 0, 0, 0);
    __builtin_amdgcn_s_setprio(0);
  }

  const int rowb = mbase + WM * 64;
  const int colb = nbase + WN * 96;
#pragma unroll
  for (int j = 0; j < 6; ++j) {
    float bj = bias[colb + j * 16 + lo];
#pragma unroll
    for (int i = 0; i < 4; ++i)
#pragma unroll
      for (int r = 0; r < 4; ++r) {
        int row = rowb + i * 16 + hi * 4 + r;  // C/D: col=lane&15, row=(lane>>4)*4+reg
        C[(size_t)row * 6144 + colb + j * 16 + lo] = f2b(acc[i][j][r] + bj);
      }
  }
}

// ---------------- RMSNorm + RoPE + split ----------------
// qkv[t][o] bf16, o = h*384 + dd*3 + j (j in {q,k,v}). One wave per (b,n,h),
// 4 waves per block; lane handles pair dd = 2l, 2l+1. Writes Q,K,V in
// [b*h][n][128] bf16. Q pre-scaled by ATT_SCALE*LOG2E.
__global__ __launch_bounds__(256) void k_normrope(const unsigned short* __restrict__ qkv,
                                                  const float* __restrict__ qw,
                                                  const float* __restrict__ kw,
                                                  const float* __restrict__ rot,
                                                  unsigned short* __restrict__ Q,
                                                  unsigned short* __restrict__ K,
                                                  unsigned short* __restrict__ V) {
  const int l = threadIdx.x & 63;
  const int idx = blockIdx.x * 4 + (threadIdx.x >> 6);
  const int h = idx & 15;
  const int n = (idx >> 4) & 2047;
  const int b = idx >> 15;
  const unsigned* p = (const unsigned*)(qkv + (size_t)(b * 2048 + n) * 6144 + h * 384 + l * 6);
  unsigned u0 = p[0], u1 = p[1], u2 = p[2];
  float q0 = b2f(u0 & 0xffff), k0 = b2f(u0 >> 16);
  float v0 = b2f(u1 & 0xffff), q1 = b2f(u1 >> 16);
  float k1 = b2f(u2 & 0xffff), v1 = b2f(u2 >> 16);
  (void)v0; (void)v1;
  float sq = q0 * q0 + q1 * q1, sk = k0 * k0 + k1 * k1;
#pragma unroll
  for (int m = 1; m < 64; m <<= 1) {
    sq += __shfl_xor(sq, m, 64);
    sk += __shfl_xor(sk, m, 64);
  }
  float qi = rsqrtf(sq * (1.0f / 128.0f) + 1e-6f) * QSCALE;  // softmax scale folded in
  float ki = rsqrtf(sk * (1.0f / 128.0f) + 1e-6f);
  float2 qwv = *(const float2*)&qw[2 * l];
  float2 kwv = *(const float2*)&kw[2 * l];
  float4 r = *(const float4*)&rot[n * 256 + l * 4];  // [cos, -sin, sin, cos]
  float qn0 = q0 * qi * qwv.x, qn1 = q1 * qi * qwv.y;
  float kn0 = k0 * ki * kwv.x, kn1 = k1 * ki * kwv.y;
  unsigned qo = (unsigned)f2b(r.x * qn0 + r.y * qn1) | ((unsigned)f2b(r.z * qn0 + r.w * qn1) << 16);
  unsigned ko = (unsigned)f2b(r.x * kn0 + r.y * kn1) | ((unsigned)f2b(r.z * kn0 + r.w * kn1) << 16);
  unsigned vo = (u1 & 0xffffu) | (u2 & 0xffff0000u);  // v passthrough (already bf16)
  size_t ob = ((size_t)(b * 16 + h) * 2048 + n) * 128 + 2 * l;
  *(unsigned*)(Q + ob) = qo;
  *(unsigned*)(K + ob) = ko;
  *(unsigned*)(V + ob) = vo;
}

// ---------------- V transpose: [bh][n][128] -> [bh][128][n] ----------------
__global__ __launch_bounds__(256) void k_transpose(const unsigned short* __restrict__ V,
                                                   unsigned short* __restrict__ Vt) {
  __shared__ unsigned short tile[64 * 66];
  const int t = threadIdx.x;
  const int d0 = blockIdx.x * 64;
  const int n0 = blockIdx.y * 64;
  const int bh = blockIdx.z;
#pragma unroll
  for (int s = t; s < 512; s += 256) {
    int nr = s >> 3, c8 = (s & 7) * 8;
    uint4 vv = *(const uint4*)(V + ((size_t)bh * 2048 + n0 + nr) * 128 + d0 + c8);
    unsigned* tp = (unsigned*)&tile[nr * 66 + c8];
    tp[0] = vv.x; tp[1] = vv.y; tp[2] = vv.z; tp[3] = vv.w;
  }
  __syncthreads();
#pragma unroll
  for (int s = t; s < 512; s += 256) {
    int dr = s >> 3, n8 = (s & 7) * 8;
    unsigned short e[8];
#pragma unroll
    for (int j = 0; j < 8; ++j) e[j] = tile[(n8 + j) * 66 + dr];
    uint4 o;
    o.x = e[0] | ((unsigned)e[1] << 16);
    o.y = e[2] | ((unsigned)e[3] << 16);
    o.z = e[4] | ((unsigned)e[5] << 16);
    o.w = e[6] | ((unsigned)e[7] << 16);
    *(uint4*)(Vt + ((size_t)bh * 128 + d0 + dr) * 2048 + n0 + n8) = o;
  }
}

// ---------------- flash attention ----------------
// R11: 4 waves (256 thr), dual-q (32 q-rows/wave as two 16-row groups),
// QBLK=128, KV tiles of 64 double-buffered (8 gl16/thread/tile), 80KB LDS
// -> 2 blocks/CU. FIXED-M softmax: p = exp2(S - M), M = static bound
// 128*max|qw|*max|kw|*QSCALE (RMSNorm rows ||q^||<=sqrt(128), RoPE
// orthogonal; softmax shift-invariant) computed in-prologue by every wave
// (R19: k_mbound folded in; hidden under stage(0) latency). Per tile the
// softmax is purely lane-local exp+add+pack; l accumulated per-lane with a
// single cross-lane reduce after the KV loop. O staging rows padded to 132.
// All LDS tiles XOR-swizzled: element_off_in_row ^= ((row & 7) << 3).
// Grid 512 = 16 qt x 32 bh, decoded so a head's 16 q-blocks share one XCD.
__global__ __launch_bounds__(256, 2) void k_attn(const unsigned short* __restrict__ Q,
                                                 const unsigned short* __restrict__ K,
                                                 const unsigned short* __restrict__ Vt,
                                                 const float* __restrict__ qw,
                                                 const float* __restrict__ kw,
                                                 float* __restrict__ out) {
  __shared__ __align__(16) unsigned short lds[40960];  // 80KB
  unsigned short* Ps = lds + 32768;                    // 4 waves x 2 x [16][64]
  const int tid = threadIdx.x;
  const int w = tid >> 6, l = tid & 63;
  const int lo = l & 15, hi = l >> 4;
  const int swz = (lo & 7) << 3;       // read-side XOR for row = ...+lo tiles
  // XCD-aware decode: 512 blocks; bh = (id&7)*4 + ((id>>3)&3), qt = id>>5
  // -> the 16 qt blocks of one bh share id%8 -> same XCD (KV 4MB = one L2).
  const int id = blockIdx.x;
  const int bh = (id & 7) * 4 + ((id >> 3) & 3);
  const int qt = id >> 5;
  const unsigned short* Qb = Q + (size_t)bh * 2048 * 128;
  const unsigned short* Kb = K + (size_t)bh * 2048 * 128;
  const unsigned short* Vb = Vt + (size_t)bh * 128 * 2048;
  unsigned short* Pswa = Ps + w * 2048;
  unsigned short* Pswb = Pswa + 1024;

  // Per-thread pre-swizzled source pointers. Row offsets added later (round
  // steps 16/32 rows, tile steps 64 rows) are multiples of 8, so the
  // swizzle XOR term (row&7) is invariant.
  const int krow0 = w * 4 + hi;             // K row within 16-row round
  const int vrow0 = w * 8 + (l >> 3);       // Vt row within 32-row round
  const unsigned short* kp = Kb + (size_t)krow0 * 128 + ((lo * 8) ^ ((krow0 & 7) << 3));
  const unsigned short* vp = Vb + (size_t)vrow0 * 2048 + (((l & 7) * 8) ^ ((vrow0 & 7) << 3));

  // stage KV tile t into buffer b: K[64][128] in 4 rounds of 16 rows,
  // Vts[128][64] in 4 rounds of 32 rows (256 threads).
  auto stage = [&](int t, int b) {
    unsigned short* Ksb = lds + b * 16384;
    unsigned short* Vtsb = Ksb + 8192;
#pragma unroll
    for (int r = 0; r < 4; ++r) {
      gl16(kp + (size_t)t * 8192 + r * 2048,            // 16 rows * 128 per round
           Ksb + (r * 16 + w * 4) * 128);
      gl16(vp + (size_t)r * 65536 + t * 64,             // 32 rows * 2048 per round
           Vtsb + (r * 32 + w * 8) * 64);
    }
  };

  stage(0, 0);   // issue first tile's loads before the M reduce (hides HBM lat)

  // R19: static softmax bound computed in-prologue (was k_mbound).
  float mq = fmaxf(fabsf(qw[l]), fabsf(qw[l + 64]));
  float mk = fmaxf(fabsf(kw[l]), fabsf(kw[l + 64]));
#pragma unroll
  for (int m = 1; m < 64; m <<= 1) {
    mq = fmaxf(mq, __shfl_xor(mq, m, 64));
    mk = fmaxf(mk, __shfl_xor(mk, m, 64));
  }
  const float M = 128.0f * mq * mk * QSCALE;

  bf16x8 qfa[4], qfb[4];
  const int qrow = qt * 128 + w * 32 + lo;
#pragma unroll
  for (int dk = 0; dk < 4; ++dk) {
    qfa[dk] = *(const bf16x8*)&Qb[(size_t)qrow * 128 + dk * 32 + hi * 8];
    qfb[dk] = *(const bf16x8*)&Qb[(size_t)(qrow + 16) * 128 + dk * 32 + hi * 8];
  }

  f32x4 Oa[8] = {}, Ob[8] = {};
  float l_a = 0.0f, l_b = 0.0f;        // per-lane partial denominators

  // fixed-M P-store for one 16-q group: lane-local only.
  auto pstore = [&](f32x4* S, float& l_part, unsigned short* Psw_) {
#pragma unroll
    for (int kf = 0; kf < 4; ++kf) {
      float p0 = exp2f(S[kf][0] - M);
      float p1 = exp2f(S[kf][1] - M);
      float p2 = exp2f(S[kf][2] - M);
      float p3 = exp2f(S[kf][3] - M);
      l_part += (p0 + p1) + (p2 + p3);
      bf16x4 pk;
      pk[0] = (__bf16)p0; pk[1] = (__bf16)p1;
      pk[2] = (__bf16)p2; pk[3] = (__bf16)p3;
      *(bf16x4*)&Psw_[lo * 64 + ((kf * 16 + hi * 4) ^ swz)] = pk;
    }
  };

  int cur = 0;
  for (int t = 0; t < 32; ++t) {
    // __syncthreads drains vmcnt(0)+lgkmcnt(0): staging from last iteration
    // had a full compute phase of slack; all reads of buffer cur^1 are done.
    __syncthreads();
    if (t + 1 < 32) stage(t + 1, cur ^ 1);
    const unsigned short* Ks = lds + cur * 16384;
    const unsigned short* Vts = Ks + 8192;

    f32x4 Sa[4] = {}, Sb[4] = {};
#pragma unroll
    for (int kf = 0; kf < 4; ++kf)
#pragma unroll
      for (int dk = 0; dk < 4; ++dk) {
        const bf16x8 kfrag =
            *(const bf16x8*)&Ks[(kf * 16 + lo) * 128 + ((dk * 32 + hi * 8) ^ swz)];
        Sa[kf] = __builtin_amdgcn_mfma_f32_16x16x32_bf16(kfrag, qfa[dk], Sa[kf], 0, 0, 0);
        Sb[kf] = __builtin_amdgcn_mfma_f32_16x16x32_bf16(kfrag, qfb[dk], Sb[kf], 0, 0, 0);
      }

    pstore(Sa, l_a, Pswa);
    pstore(Sb, l_b, Pswb);

    const bf16x8 pa0 = *(const bf16x8*)&Pswa[lo * 64 + ((hi * 8) ^ swz)];
    const bf16x8 pa1 = *(const bf16x8*)&Pswa[lo * 64 + ((32 + hi * 8) ^ swz)];
    const bf16x8 pb0 = *(const bf16x8*)&Pswb[lo * 64 + ((hi * 8) ^ swz)];
    const bf16x8 pb1 = *(const bf16x8*)&Pswb[lo * 64 + ((32 + hi * 8) ^ swz)];
#pragma unroll
    for (int df = 0; df < 8; ++df) {
      const bf16x8 v0 = *(const bf16x8*)&Vts[(df * 16 + lo) * 64 + ((hi * 8) ^ swz)];
      const bf16x8 v1 = *(const bf16x8*)&Vts[(df * 16 + lo) * 64 + ((32 + hi * 8) ^ swz)];
      Oa[df] = __builtin_amdgcn_mfma_f32_16x16x32_bf16(v0, pa0, Oa[df], 0, 0, 0);
      Oa[df] = __builtin_amdgcn_mfma_f32_16x16x32_bf16(v1, pa1, Oa[df], 0, 0, 0);
      Ob[df] = __builtin_amdgcn_mfma_f32_16x16x32_bf16(v0, pb0, Ob[df], 0, 0, 0);
      Ob[df] = __builtin_amdgcn_mfma_f32_16x16x32_bf16(v1, pb1, Ob[df], 0, 0, 0);
    }
    cur ^= 1;
  }

  // single cross-lane denominator reduce (over the 4 hi groups)
  l_a += __shfl_xor(l_a, 16, 64);
  l_a += __shfl_xor(l_a, 32, 64);
  l_b += __shfl_xor(l_b, 16, 64);
  l_b += __shfl_xor(l_b, 32, 64);
  const float inva = 1.0f / l_a;   // valid for q = lo (replicated across hi)
  const float invb = 1.0f / l_b;
  const int b = bh >> 4, h = bh & 15;
  const int q2 = l >> 2, c = (l & 3) * 32;
  float* Ot = ((float*)lds) + w * 2112;  // [16 q][132 dv pad] per wave (~8.25KB)

  // group A epilogue
  __syncthreads();                 // done with K/V bufs; reuse as fp32 staging
#pragma unroll
  for (int df = 0; df < 8; ++df)
#pragma unroll
    for (int r = 0; r < 4; ++r)
      Ot[lo * 132 + df * 16 + hi * 4 + r] = Oa[df][r] * inva;
  __syncthreads();
  {
    float* op = out + ((size_t)(b * 2048 + qt * 128 + w * 32 + q2) * 2048 + h * 128 + c);
#pragma unroll
    for (int u = 0; u < 8; ++u)
      *(float4*)&op[u * 4] = *(const float4*)&Ot[q2 * 132 + c + u * 4];
  }
  // group B epilogue
  __syncthreads();
#pragma unroll
  for (int df = 0; df < 8; ++df)
#pragma unroll
    for (int r = 0; r < 4; ++r)
      Ot[lo * 132 + df * 16 + hi * 4 + r] = Ob[df][r] * invb;
  __syncthreads();
  {
    float* op = out + ((size_t)(b * 2048 + qt * 128 + w * 32 + 16 + q2) * 2048 + h * 128 + c);
#pragma unroll
    for (int u = 0; u < 8; ++u)
      *(float4*)&op[u * 4] = *(const float4*)&Ot[q2 * 132 + c + u * 4];
  }
}

// ---------------------------------------------------------------------------
extern "C" void kernel_launch(void* const* d_in, const int* in_sizes, int n_in,
                              void* d_out, int out_size, void* d_ws, size_t ws_size,
                              hipStream_t stream) {
  (void)in_sizes; (void)n_in; (void)out_size; (void)ws_size;
  const float* x = (const float*)d_in[0];
  const float* qkv_w = (const float*)d_in[1];
  const float* qkv_b = (const float*)d_in[2];
  const float* q_norm_w = (const float*)d_in[3];
  const float* k_norm_w = (const float*)d_in[4];
  const float* rot = (const float*)d_in[5];
  float* out = (float*)d_out;
  char* ws = (char*)d_ws;
  // ws layout (bytes): xb 16MB | wb 24MB | qkv 48MB | Q 16MB | K 16MB | V 16MB
  // Vt aliases xb region (dead after GEMM). Total required: ~136 MiB.
  unsigned short* xb  = (unsigned short*)(ws);
  unsigned short* wb  = (unsigned short*)(ws + 16777216);
  unsigned short* qkv = (unsigned short*)(ws + 41943040);
  unsigned short* Qb  = (unsigned short*)(ws + 92274688);
  unsigned short* Kb  = (unsigned short*)(ws + 109051904);
  unsigned short* Vb  = (unsigned short*)(ws + 125829120);
  unsigned short* Vtb = (unsigned short*)(ws);  // alias

  hipLaunchKernelGGL(k_cvt2, dim3(2048), dim3(256), 0, stream,
                     (const float4*)x, (ushort4*)xb, 8388608 / 4,
                     (const float4*)qkv_w, (ushort4*)wb, 12582912 / 4);
  hipLaunchKernelGGL(k_gemm, dim3(512), dim3(512), 0, stream, xb, wb, qkv_b, qkv);
  hipLaunchKernelGGL(k_normrope, dim3(16384), dim3(256), 0, stream,
                     qkv, q_norm_w, k_norm_w, rot, Qb, Kb, Vb);
  hipLaunchKernelGGL(k_transpose, dim3(2, 32, 32), dim3(256), 0, stream, Vb, Vtb);
  hipLaunchKernelGGL(k_attn, dim3(512), dim3(256), 0, stream, Qb, Kb, Vtb,
                     q_norm_w, k_norm_w, out);
}